// Round 7
// baseline (247.282 us; speedup 1.0000x reference)
//
#include <hip/hip_runtime.h>
#include <hip/hip_bf16.h>
#include <math.h>

typedef unsigned int   u32;
typedef unsigned short u16;
typedef __bf16 bf16;
typedef bf16  bf16x8  __attribute__((ext_vector_type(8)));
typedef float f32x4   __attribute__((ext_vector_type(4)));
typedef float f32x16  __attribute__((ext_vector_type(16)));

#define BBATCH 16
#define MTOK   16
#define NEXP   16
#define DDIM   512
#define HDIM   682
#define HPAD   704            // 11*64
#define NHCOL  (NEXP*HDIM)    // 10912
#define NHPCOL (NEXP*HPAD)    // 11264

__device__ __forceinline__ u16 f2bf(float f) {
    u32 u = __builtin_bit_cast(u32, f);
    u += 0x7fffu + ((u >> 16) & 1u);
    return (u16)(u >> 16);
}
__device__ __forceinline__ float bf2f(u16 h) {
    u32 u = ((u32)h) << 16;
    return __builtin_bit_cast(float, u);
}
__device__ __forceinline__ u32 pk2bf(float a, float b) {
    __hip_bfloat162 t = __float22bfloat162_rn(float2{a, b});
    u32 r;
    __builtin_memcpy(&r, &t, 4);
    return r;
}

// ---------------------------------------------------------------------------
// k_prep: x -> xh/xl bf16 planes; Y = sum_n b2; out = bout; DwT pad zeros.
// grid 760
// ---------------------------------------------------------------------------
__global__ __launch_bounds__(256) void k_prep(
    const float* __restrict__ x, const float* __restrict__ b2,
    const float* __restrict__ bout,
    u16* __restrict__ xh, u16* __restrict__ xl,
    float* __restrict__ Y, float* __restrict__ out, u16* __restrict__ DwT) {
    const int bid = blockIdx.x, tid = threadIdx.x;
    if (bid < 128) {
        int i = (bid * 256 + tid) * 4;
        float4 v = *(const float4*)&x[i];
        float a[4] = {v.x, v.y, v.z, v.w};
        u16 hh[4], ll[4];
        #pragma unroll
        for (int j = 0; j < 4; ++j) {
            hh[j] = f2bf(a[j]);
            ll[j] = f2bf(a[j] - bf2f(hh[j]));
        }
        *(uint2*)&xh[i] = make_uint2((u32)hh[0] | ((u32)hh[1] << 16), (u32)hh[2] | ((u32)hh[3] << 16));
        *(uint2*)&xl[i] = make_uint2((u32)ll[0] | ((u32)ll[1] << 16), (u32)ll[2] | ((u32)ll[3] << 16));
    } else if (bid < 640) {
        int idx = (bid - 128) * 256 + tid;
        int d = idx & 511;
        float s = 0.f;
        #pragma unroll
        for (int nn = 0; nn < 16; ++nn) s += b2[nn * 512 + d];
        Y[idx] = s;
    } else if (bid < 672) {
        int idx = (bid - 640) * 256 + tid;
        out[idx] = bout[idx & 511];
    } else {
        int g = (bid - 672) * 256 + tid;           // 8B chunks of DwT pad
        int bn = g / 88, off = g - bn * 88;
        *(uint2*)(DwT + (size_t)(bn * HPAD + HDIM) * 16 + off * 4) = make_uint2(0u, 0u);
    }
}

// ---------------------------------------------------------------------------
// k_lt1 (grid 1056): two GEMMs, XCD-swizzled, direct strided B loads,
// double-buffered LDS, ONE barrier per K-step, PREFETCH DEPTH ~1.5 steps
// (two static register stages, manual unroll-2).
//  [0,704):    logits 64x64 tiles (split-bf16 3-product) + fused Dw softmax
//  [704,1056): T1b = xh * W1^T, 128x64 tiles
// ---------------------------------------------------------------------------
__global__ __launch_bounds__(256) void k_lt1(
    const u16* __restrict__ xh, const u16* __restrict__ xl,
    const float* __restrict__ phi, const float* __restrict__ W1,
    float* __restrict__ logits, u16* __restrict__ DwT, u16* __restrict__ T1b) {
    __shared__ __align__(16) u16 S[20480];   // 40960 B
    const int bid = blockIdx.x, tid = threadIdx.x;
    const int wv = tid >> 6, lane = tid & 63, quad = lane >> 4, l15 = lane & 15;
    if (bid < 704) {
        const int xcd = bid & 7, slot = bid >> 3;
        const int rt = slot & 3, ct = (slot >> 2) * 8 + xcd;
        if (ct >= 171) return;                     // 20 hole blocks
        const int r = tid >> 2, kg = (tid & 3) * 8;
        const u16* aph = xh + (size_t)(rt * 64 + r) * 512 + kg;
        const u16* apl = xl + (size_t)(rt * 64 + r) * 512 + kg;
        const int cc = tid & 63, q8 = (tid >> 6) * 8;
        const int c = ct * 64 + cc;
        auto loadB = [&](int kb, float* vB) {
            const float* src = phi + (size_t)(kb + q8) * NHCOL + c;
            #pragma unroll
            for (int i = 0; i < 8; ++i)
                vB[i] = (c < NHCOL) ? src[(size_t)i * NHCOL] : 0.f;
        };
        auto STAGE = [&](int p, const uint4& Ah, const uint4& Al, const float* vB) {
            *(uint4*)&S[p + r * 40 + kg]        = Ah;
            *(uint4*)&S[5120 + p + r * 40 + kg] = Al;
            u16 th[8], tl[8];
            #pragma unroll
            for (int i = 0; i < 8; ++i) {
                th[i] = f2bf(vB[i]);
                tl[i] = f2bf(vB[i] - bf2f(th[i]));
            }
            *(uint4*)&S[10240 + p + cc * 40 + q8] = *(uint4*)&th[0];
            *(uint4*)&S[15360 + p + cc * 40 + q8] = *(uint4*)&tl[0];
        };
        f32x4 acc[4] = {};
        auto MF = [&](int p) {
            bf16x8 ah = *(const bf16x8*)&S[p + (wv * 16 + l15) * 40 + quad * 8];
            bf16x8 al = *(const bf16x8*)&S[5120 + p + (wv * 16 + l15) * 40 + quad * 8];
            #pragma unroll
            for (int j = 0; j < 4; ++j) {
                bf16x8 bh = *(const bf16x8*)&S[10240 + p + (j * 16 + l15) * 40 + quad * 8];
                bf16x8 bl = *(const bf16x8*)&S[15360 + p + (j * 16 + l15) * 40 + quad * 8];
                acc[j] = __builtin_amdgcn_mfma_f32_16x16x32_bf16(ah, bh, acc[j], 0, 0, 0);
                acc[j] = __builtin_amdgcn_mfma_f32_16x16x32_bf16(ah, bl, acc[j], 0, 0, 0);
                acc[j] = __builtin_amdgcn_mfma_f32_16x16x32_bf16(al, bh, acc[j], 0, 0, 0);
            }
        };
        uint4 Ah0, Al0, Ah1, Al1;
        float vB0[8], vB1[8];
        Ah0 = *(const uint4*)aph;        Al0 = *(const uint4*)apl;        loadB(0, vB0);
        Ah1 = *(const uint4*)(aph + 32); Al1 = *(const uint4*)(apl + 32); loadB(32, vB1);
        for (int s = 0; s < 16; s += 2) {
            STAGE(0, Ah0, Al0, vB0);
            __syncthreads();
            if (s + 2 < 16) {
                Ah0 = *(const uint4*)(aph + (s + 2) * 32);
                Al0 = *(const uint4*)(apl + (s + 2) * 32);
                loadB((s + 2) * 32, vB0);
            }
            MF(0);
            STAGE(2560, Ah1, Al1, vB1);
            __syncthreads();
            if (s + 3 < 16) {
                Ah1 = *(const uint4*)(aph + (s + 3) * 32);
                Al1 = *(const uint4*)(apl + (s + 3) * 32);
                loadB((s + 3) * 32, vB1);
            }
            MF(2560);
        }
        // epilogue: logits + fused Dw softmax over m
        const int b  = rt * 4 + wv;
        const int r0 = rt * 64 + wv * 16 + quad * 4;
        #pragma unroll
        for (int j = 0; j < 4; ++j) {
            const int col = ct * 64 + j * 16 + l15;
            float a0 = acc[j][0], a1 = acc[j][1], a2 = acc[j][2], a3 = acc[j][3];
            if (col < NHCOL) {
                logits[(size_t)(r0 + 0) * NHCOL + col] = a0;
                logits[(size_t)(r0 + 1) * NHCOL + col] = a1;
                logits[(size_t)(r0 + 2) * NHCOL + col] = a2;
                logits[(size_t)(r0 + 3) * NHCOL + col] = a3;
            }
            float mx = fmaxf(fmaxf(a0, a1), fmaxf(a2, a3));
            mx = fmaxf(mx, __shfl_xor(mx, 16));
            mx = fmaxf(mx, __shfl_xor(mx, 32));
            float e0 = expf(a0 - mx), e1 = expf(a1 - mx);
            float e2 = expf(a2 - mx), e3 = expf(a3 - mx);
            float s = e0 + e1 + e2 + e3;
            s += __shfl_xor(s, 16);
            s += __shfl_xor(s, 32);
            float inv = 1.f / s;
            if (col < NHCOL) {
                int n = col / HDIM;
                int p2 = col - n * HDIM;
                u16* dst = DwT + ((size_t)((b * 16 + n) * HPAD + p2)) * 16 + quad * 4;
                *(uint2*)dst = make_uint2(pk2bf(e0 * inv, e1 * inv), pk2bf(e2 * inv, e3 * inv));
            }
        }
    } else {
        // T1: 128x64 tile, direct strided W1 loads, dbuf, prefetch-2
        const int b2_ = bid - 704;
        const int xcd = b2_ & 7, slot = b2_ >> 3;
        const int rh = slot & 1, ct = (slot >> 1) * 8 + xcd;   // 0..175 exact
        const int n = ct / 11, h0 = (ct % 11) * 64;
        const int r = tid >> 1, kg = (tid & 1) * 16;
        const u16* ap = xh + (size_t)(rh * 128 + r) * 512 + kg;
        const int cc = tid & 63, q8 = (tid >> 6) * 8;
        const int h = h0 + cc;
        auto loadB = [&](int kb, float* vB) {
            const float* src = W1 + ((size_t)n * 512 + kb + q8) * HDIM + h;
            #pragma unroll
            for (int i = 0; i < 8; ++i)
                vB[i] = (h < HDIM) ? src[(size_t)i * HDIM] : 0.f;
        };
        auto STAGE = [&](int pA, int pB, const uint4& A0, const uint4& A1, const float* vB) {
            *(uint4*)&S[pA + r * 40 + kg]     = A0;
            *(uint4*)&S[pA + r * 40 + kg + 8] = A1;
            u16 tv[8];
            #pragma unroll
            for (int i = 0; i < 8; ++i) tv[i] = f2bf(vB[i]);
            *(uint4*)&S[pB + cc * 40 + q8] = *(uint4*)&tv[0];
        };
        f32x4 acc[2][4] = {};
        auto MF = [&](int pA, int pB) {
            bf16x8 af[2], bfr[4];
            #pragma unroll
            for (int i = 0; i < 2; ++i)
                af[i] = *(const bf16x8*)&S[pA + (wv * 32 + i * 16 + l15) * 40 + quad * 8];
            #pragma unroll
            for (int j = 0; j < 4; ++j)
                bfr[j] = *(const bf16x8*)&S[pB + (j * 16 + l15) * 40 + quad * 8];
            #pragma unroll
            for (int i = 0; i < 2; ++i)
                #pragma unroll
                for (int j = 0; j < 4; ++j)
                    acc[i][j] = __builtin_amdgcn_mfma_f32_16x16x32_bf16(af[i], bfr[j], acc[i][j], 0, 0, 0);
        };
        uint4 A00, A01, A10, A11;
        float vB0[8], vB1[8];
        A00 = *(const uint4*)ap;        A01 = *(const uint4*)(ap + 8);  loadB(0, vB0);
        A10 = *(const uint4*)(ap + 32); A11 = *(const uint4*)(ap + 40); loadB(32, vB1);
        for (int s = 0; s < 16; s += 2) {
            STAGE(0, 10240, A00, A01, vB0);
            __syncthreads();
            if (s + 2 < 16) {
                A00 = *(const uint4*)(ap + (s + 2) * 32);
                A01 = *(const uint4*)(ap + (s + 2) * 32 + 8);
                loadB((s + 2) * 32, vB0);
            }
            MF(0, 10240);
            STAGE(5120, 12800, A10, A11, vB1);
            __syncthreads();
            if (s + 3 < 16) {
                A10 = *(const uint4*)(ap + (s + 3) * 32);
                A11 = *(const uint4*)(ap + (s + 3) * 32 + 8);
                loadB((s + 3) * 32, vB1);
            }
            MF(5120, 12800);
        }
        #pragma unroll
        for (int i = 0; i < 2; ++i)
            #pragma unroll
            for (int j = 0; j < 4; ++j) {
                int col = ct * 64 + j * 16 + l15;   // padded col = n*704+h
                int r0  = rh * 128 + wv * 32 + i * 16 + quad * 4;
                #pragma unroll
                for (int rr = 0; rr < 4; ++rr)
                    T1b[(size_t)(r0 + rr) * NHPCOL + col] = f2bf(acc[i][j][rr]);
            }
    }
}

// ---------------------------------------------------------------------------
// k_cw (grid 256 x 512 threads): Cw = softmax_p(softmax_n(logits)) -> CwB
// 512 threads raises per-CU wave count (1 block/CU) to 8 waves.
// ---------------------------------------------------------------------------
__global__ __launch_bounds__(512) void k_cw(
    const float* __restrict__ L, u16* __restrict__ CwB) {
    __shared__ __align__(16) float row[NHCOL];
    const int bid = blockIdx.x, tid = threadIdx.x;
    const int m = bid & 15, b = bid >> 4;
    const float* Lrow = L + (size_t)(b * 16 + m) * NHCOL;
    for (int i4 = tid; i4 < NHCOL / 4; i4 += 512)
        *(float4*)&row[i4 * 4] = *(const float4*)&Lrow[i4 * 4];
    __syncthreads();
    for (int p = tid; p < HDIM; p += 512) {
        float v[16];
        float mx = -1e30f;
        #pragma unroll
        for (int n = 0; n < 16; ++n) { v[n] = row[n * HDIM + p]; mx = fmaxf(mx, v[n]); }
        float s = 0.f;
        #pragma unroll
        for (int n = 0; n < 16; ++n) { v[n] = expf(v[n] - mx); s += v[n]; }
        float inv = 1.f / s;
        #pragma unroll
        for (int n = 0; n < 16; ++n) row[n * HDIM + p] = expf(v[n] * inv);  // cache exp(s1)
    }
    __syncthreads();
    const int wv = tid >> 6, lane = tid & 63;
    for (int nn = 0; nn < 2; ++nn) {
        int n = wv * 2 + nn;
        float s = 0.f;
        for (int p = lane; p < HDIM; p += 64) s += row[n * HDIM + p];
        #pragma unroll
        for (int off = 32; off > 0; off >>= 1) s += __shfl_xor(s, off);
        float inv = 1.f / s;
        u16* dst = CwB + (size_t)(((b * 16 + n) * 16 + m)) * HPAD;
        for (int p = lane; p < HDIM; p += 64) dst[p] = f2bf(row[n * HDIM + p] * inv);
        if (lane < HPAD - HDIM) dst[HDIM + lane] = 0;
    }
}

// ---------------------------------------------------------------------------
// Fused middle (grid 1536 flat, XCD-grouped: 6 ht-siblings of one (b,n)):
//  stage1: hmid = relu(b1 + Dw^T·T1) via 32x32x16; stage2: G += Cw·hmid
// ---------------------------------------------------------------------------
__global__ __launch_bounds__(256) void k_mid(
    const u16* __restrict__ T1b, const u16* __restrict__ DwT,
    const u16* __restrict__ CwB, const float* __restrict__ b1,
    u16* __restrict__ Gb) {
    __shared__ u16 T1T[128 * 24];
    __shared__ u16 hmidT[128 * 64];
    const int bid = blockIdx.x;
    const int xcd = bid & 7, slot = bid >> 3;
    const int ht = slot % 6, gg = slot / 6;
    const int g = gg * 8 + xcd;
    const int n = g & 15, b = g >> 4;
    const int tid = threadIdx.x;
    const int wv = tid >> 6, lane = tid & 63;
    const int quad = lane >> 4, l15 = lane & 15;
    const int l31 = lane & 31, half = lane >> 5;
    const int h0 = ht * 128;
    const int b16n = b * 16 + n;

    {
        int m = tid & 15, hh0 = (tid >> 4) * 8;
        u16 v[8];
        if (h0 + hh0 + 8 <= HPAD) {
            *(uint4*)v = *(const uint4*)(T1b + (size_t)(b * 16 + m) * NHPCOL + n * HPAD + h0 + hh0);
        } else {
            #pragma unroll
            for (int i = 0; i < 8; ++i) v[i] = 0;
        }
        #pragma unroll
        for (int i = 0; i < 8; ++i) T1T[(hh0 + i) * 24 + m] = v[i];
    }
    __syncthreads();

    const int hrow = wv * 32 + l31;
    bf16x8 bt1 = *(const bf16x8*)&T1T[hrow * 24 + half * 8];
    int hg1 = h0 + hrow;
    float biasf = (hg1 < HDIM) ? b1[n * HDIM + hg1] : 0.f;
    f32x16 cbias;
    #pragma unroll
    for (int i = 0; i < 16; ++i) cbias[i] = biasf;

    const u16* dwbase = DwT + (size_t)(b16n * HPAD) * 16;
    const u16* cwrow  = CwB + (size_t)(b16n * 16 + l15) * HPAD;

    f32x4 acc[2] = {};
    const int hsw = hrow & 7;
    for (int c = 0; c < 11; ++c) {
        const int p0 = c * 64;
        #pragma unroll
        for (int pt = 0; pt < 2; ++pt) {
            bf16x8 adw = *(const bf16x8*)(dwbase + (size_t)(p0 + pt * 32 + l31) * 16 + half * 8);
            f32x16 hm = __builtin_amdgcn_mfma_f32_32x32x16_bf16(adw, bt1, cbias, 0, 0, 0);
            #pragma unroll
            for (int g2 = 0; g2 < 4; ++g2) {
                float v0 = fmaxf(hm[g2 * 4 + 0], 0.f);
                float v1 = fmaxf(hm[g2 * 4 + 1], 0.f);
                float v2 = fmaxf(hm[g2 * 4 + 2], 0.f);
                float v3 = fmaxf(hm[g2 * 4 + 3], 0.f);
                uint2 pk = make_uint2(pk2bf(v0, v1), pk2bf(v2, v3));
                int gran = (pt * 4 + g2) ^ hsw;
                *(uint2*)&hmidT[hrow * 64 + gran * 8 + half * 4] = pk;
            }
        }
        #pragma unroll
        for (int s = 0; s < 2; ++s) {
            bf16x8 acw = *(const bf16x8*)(cwrow + p0 + s * 32 + quad * 8);
            #pragma unroll
            for (int hj = 0; hj < 2; ++hj) {
                int hr = wv * 32 + hj * 16 + l15;
                int gr = (s * 4 + quad) ^ (hr & 7);
                bf16x8 bh = *(const bf16x8*)&hmidT[hr * 64 + gr * 8];
                acc[hj] = __builtin_amdgcn_mfma_f32_16x16x32_bf16(acw, bh, acc[hj], 0, 0, 0);
            }
        }
    }
    #pragma unroll
    for (int hj = 0; hj < 2; ++hj) {
        int h = h0 + wv * 32 + hj * 16 + l15;
        if (h < HPAD) {
            #pragma unroll
            for (int r = 0; r < 4; ++r) {
                int m = quad * 4 + r;
                Gb[(size_t)(b * 16 + m) * NHPCOL + n * HPAD + h] = f2bf(acc[hj][r]);
            }
        }
    }
}

// ---------------------------------------------------------------------------
// k_ygemm: Y[256][512] += Gb[.., n-slice] * W2[n]^T.  grid 512 flat,
// XCD-grouped. Direct strided W2 loads, dbuf LDS, prefetch-2 (unroll-2).
// ---------------------------------------------------------------------------
__global__ __launch_bounds__(256) void k_ygemm(
    const u16* __restrict__ G, const float* __restrict__ W2, float* __restrict__ Y) {
    __shared__ __align__(16) u16 S[15360];   // As p*2560; Bs 5120 + p*5120
    const int bid = blockIdx.x;
    const int xcd = bid & 7, slot = bid >> 3;
    const int rt = slot & 3, gg = slot >> 2;
    const int g = gg * 8 + xcd;
    const int ct = g & 3, nz = g >> 2;
    const int n = nz >> 1, kb0 = (nz & 1) * 352;
    const int tid = threadIdx.x;
    const int wv = tid >> 6, lane = tid & 63, quad = lane >> 4, l15 = lane & 15;
    const int m0 = rt * 64, d0 = ct * 128;
    const int am = tid >> 2, akg = (tid & 3) * 8;
    const u16* apg = G + (size_t)(m0 + am) * NHPCOL + n * HPAD + akg;
    const int dd = tid & 127, q16 = (tid >> 7) * 16;
    const int d = d0 + dd;
    auto loadB = [&](int kb, float* vB) {
        #pragma unroll
        for (int i = 0; i < 16; ++i) {
            int hh = kb + q16 + i;
            vB[i] = (hh < HDIM) ? W2[((size_t)n * HDIM + hh) * 512 + d] : 0.f;
        }
    };
    auto STAGE = [&](int pA, int pB, const uint4& A0, const float* vB) {
        *(uint4*)&S[pA + am * 40 + akg] = A0;
        u16 tv[16];
        #pragma unroll
        for (int i = 0; i < 16; ++i) tv[i] = f2bf(vB[i]);
        *(uint4*)&S[pB + dd * 40 + q16]     = *(uint4*)&tv[0];
        *(uint4*)&S[pB + dd * 40 + q16 + 8] = *(uint4*)&tv[8];
    };
    f32x4 acc[4][2] = {};
    auto MF = [&](int pA, int pB) {
        bf16x8 af[4], bfr[2];
        #pragma unroll
        for (int i = 0; i < 4; ++i) af[i] = *(const bf16x8*)&S[pA + (i * 16 + l15) * 40 + quad * 8];
        #pragma unroll
        for (int j = 0; j < 2; ++j) bfr[j] = *(const bf16x8*)&S[pB + (wv * 32 + j * 16 + l15) * 40 + quad * 8];
        #pragma unroll
        for (int i = 0; i < 4; ++i)
            #pragma unroll
            for (int j = 0; j < 2; ++j)
                acc[i][j] = __builtin_amdgcn_mfma_f32_16x16x32_bf16(af[i], bfr[j], acc[i][j], 0, 0, 0);
    };
    uint4 A0, A1;
    float vB0[16], vB1[16];
    A0 = *(const uint4*)(apg + kb0);      loadB(kb0, vB0);
    A1 = *(const uint4*)(apg + kb0 + 32); loadB(kb0 + 32, vB1);
    for (int s = 0; s < 11; s += 2) {
        STAGE(0, 5120, A0, vB0);
        __syncthreads();
        if (s + 2 < 11) {
            A0 = *(const uint4*)(apg + kb0 + (s + 2) * 32);
            loadB(kb0 + (s + 2) * 32, vB0);
        }
        MF(0, 5120);
        if (s + 1 < 11) {
            STAGE(2560, 10240, A1, vB1);
            __syncthreads();
            if (s + 3 < 11) {
                A1 = *(const uint4*)(apg + kb0 + (s + 3) * 32);
                loadB(kb0 + (s + 3) * 32, vB1);
            }
            MF(2560, 10240);
        }
    }
    #pragma unroll
    for (int i = 0; i < 4; ++i)
        #pragma unroll
        for (int j = 0; j < 2; ++j) {
            int dcol = d0 + wv * 32 + j * 16 + l15;
            int r0 = m0 + i * 16 + quad * 4;
            #pragma unroll
            for (int r = 0; r < 4; ++r)
                atomicAdd(&Y[(size_t)(r0 + r) * 512 + dcol], acc[i][j][r]);
        }
}

// ---------------------------------------------------------------------------
// k_outgemm: out[16][512] += Yflat[16][k-slice] * Wout^T.  grid (ct=4, ks=128)
// 64-wide slices; BOTH K-steps fully preloaded (no mid-kernel vmcnt stall).
// ---------------------------------------------------------------------------
__global__ __launch_bounds__(256) void k_outgemm(
    const float* __restrict__ Y, const float* __restrict__ Wout, float* __restrict__ out) {
    __shared__ __align__(16) u16 S[11520];   // As p*640; Bs 1280 + p*5120
    const int ct = blockIdx.x, ks = blockIdx.y;
    const int tid = threadIdx.x;
    const int wv = tid >> 6, lane = tid & 63, quad = lane >> 4, l15 = lane & 15;
    const int o0 = ct * 128, kbase = ks * 64;
    const int r_ = tid >> 4, k2 = (tid & 15) * 2;
    const float* ypg = Y + (size_t)r_ * 8192 + kbase + k2;
    const int dd = tid & 127, q16 = (tid >> 7) * 16;
    const int o = o0 + dd;
    auto loadB = [&](int kb, float* vB) {
        #pragma unroll
        for (int i = 0; i < 16; ++i)
            vB[i] = Wout[(size_t)(kbase + kb + q16 + i) * 512 + o];
    };
    auto STAGE = [&](int pA, int pB, const float2& ya, const float* vB) {
        S[pA + r_ * 40 + k2]     = f2bf(ya.x);
        S[pA + r_ * 40 + k2 + 1] = f2bf(ya.y);
        u16 tv[16];
        #pragma unroll
        for (int i = 0; i < 16; ++i) tv[i] = f2bf(vB[i]);
        *(uint4*)&S[pB + dd * 40 + q16]     = *(uint4*)&tv[0];
        *(uint4*)&S[pB + dd * 40 + q16 + 8] = *(uint4*)&tv[8];
    };
    f32x4 acc[2] = {};
    auto MF = [&](int pA, int pB) {
        bf16x8 af = *(const bf16x8*)&S[pA + l15 * 40 + quad * 8];
        #pragma unroll
        for (int j = 0; j < 2; ++j) {
            bf16x8 bfr = *(const bf16x8*)&S[pB + (wv * 32 + j * 16 + l15) * 40 + quad * 8];
            acc[j] = __builtin_amdgcn_mfma_f32_16x16x32_bf16(af, bfr, acc[j], 0, 0, 0);
        }
    };
    float2 ya0 = *(const float2*)ypg;
    float2 ya1 = *(const float2*)(ypg + 32);
    float vB0[16], vB1[16];
    loadB(0, vB0);
    loadB(32, vB1);
    STAGE(0, 1280, ya0, vB0);
    __syncthreads();
    MF(0, 1280);
    STAGE(640, 6400, ya1, vB1);
    __syncthreads();
    MF(640, 6400);
    #pragma unroll
    for (int j = 0; j < 2; ++j) {
        int oc = o0 + wv * 32 + j * 16 + l15;
        #pragma unroll
        for (int r = 0; r < 4; ++r)
            atomicAdd(&out[(size_t)(quad * 4 + r) * 512 + oc], acc[j][r]);
    }
}

// ---------------------------------------------------------------------------
extern "C" void kernel_launch(void* const* d_in, const int* in_sizes, int n_in,
                              void* d_out, int out_size, void* d_ws, size_t ws_size,
                              hipStream_t stream) {
    const float* x    = (const float*)d_in[0];
    const float* phi  = (const float*)d_in[1];
    const float* W1   = (const float*)d_in[2];
    const float* b1   = (const float*)d_in[3];
    const float* W2   = (const float*)d_in[4];
    const float* b2   = (const float*)d_in[5];
    const float* Wout = (const float*)d_in[6];
    const float* bout = (const float*)d_in[7];
    float* out = (float*)d_out;

    // Workspace (~35.3 MB)
    char* base = (char*)d_ws;
    float* logits = (float*)(base + 0);           // 11,173,888
    u16*   DwT    = (u16*)(base + 11173888);      //  5,767,168
    u16*   CwB    = (u16*)(base + 16941056);      //  5,767,168
    u16*   T1b    = (u16*)(base + 22708224);      //  5,767,168
    u16*   Gb     = (u16*)(base + 28475392);      //  5,767,168
    u16*   xh     = (u16*)(base + 34242560);      //    262,144
    u16*   xl     = (u16*)(base + 34504704);      //    262,144
    float* Y      = (float*)(base + 34766848);    //    524,288

    k_prep    <<<dim3(760), 256, 0, stream>>>(x, b2, bout, xh, xl, Y, out, DwT);
    k_lt1     <<<dim3(1056), 256, 0, stream>>>(xh, xl, phi, W1, logits, DwT, T1b);
    k_cw      <<<dim3(256), 512, 0, stream>>>(logits, CwB);
    k_mid     <<<dim3(1536), 256, 0, stream>>>(T1b, DwT, CwB, b1, Gb);
    k_ygemm   <<<dim3(512), 256, 0, stream>>>(Gb, W2, Y);
    k_outgemm <<<dim3(4, 128), 256, 0, stream>>>(Y, Wout, out);
}

// Round 9
// 209.523 us; speedup vs baseline: 1.1802x; 1.1802x over previous
//
#include <hip/hip_runtime.h>
#include <hip/hip_bf16.h>
#include <math.h>

typedef unsigned int   u32;
typedef unsigned short u16;
typedef __bf16 bf16;
typedef bf16  bf16x8  __attribute__((ext_vector_type(8)));
typedef float f32x4   __attribute__((ext_vector_type(4)));
typedef float f32x16  __attribute__((ext_vector_type(16)));

#define BBATCH 16
#define MTOK   16
#define NEXP   16
#define DDIM   512
#define HDIM   682
#define HPAD   704            // 11*64
#define NHCOL  (NEXP*HDIM)    // 10912
#define NHPCOL (NEXP*HPAD)    // 11264

__device__ __forceinline__ u16 f2bf(float f) {
    u32 u = __builtin_bit_cast(u32, f);
    u += 0x7fffu + ((u >> 16) & 1u);
    return (u16)(u >> 16);
}
__device__ __forceinline__ float bf2f(u16 h) {
    u32 u = ((u32)h) << 16;
    return __builtin_bit_cast(float, u);
}
__device__ __forceinline__ u32 pk2bf(float a, float b) {
    __hip_bfloat162 t = __float22bfloat162_rn(float2{a, b});
    u32 r;
    __builtin_memcpy(&r, &t, 4);
    return r;
}

// ---------------------------------------------------------------------------
// k_prep: x -> xh/xl bf16 planes; Y = sum_n b2; out = bout; DwT pad zeros.
// grid 760
// ---------------------------------------------------------------------------
__global__ __launch_bounds__(256) void k_prep(
    const float* __restrict__ x, const float* __restrict__ b2,
    const float* __restrict__ bout,
    u16* __restrict__ xh, u16* __restrict__ xl,
    float* __restrict__ Y, float* __restrict__ out, u16* __restrict__ DwT) {
    const int bid = blockIdx.x, tid = threadIdx.x;
    if (bid < 128) {
        int i = (bid * 256 + tid) * 4;
        float4 v = *(const float4*)&x[i];
        float a[4] = {v.x, v.y, v.z, v.w};
        u16 hh[4], ll[4];
        #pragma unroll
        for (int j = 0; j < 4; ++j) {
            hh[j] = f2bf(a[j]);
            ll[j] = f2bf(a[j] - bf2f(hh[j]));
        }
        *(uint2*)&xh[i] = make_uint2((u32)hh[0] | ((u32)hh[1] << 16), (u32)hh[2] | ((u32)hh[3] << 16));
        *(uint2*)&xl[i] = make_uint2((u32)ll[0] | ((u32)ll[1] << 16), (u32)ll[2] | ((u32)ll[3] << 16));
    } else if (bid < 640) {
        int idx = (bid - 128) * 256 + tid;
        int d = idx & 511;
        float s = 0.f;
        #pragma unroll
        for (int nn = 0; nn < 16; ++nn) s += b2[nn * 512 + d];
        Y[idx] = s;
    } else if (bid < 672) {
        int idx = (bid - 640) * 256 + tid;
        out[idx] = bout[idx & 511];
    } else {
        int g = (bid - 672) * 256 + tid;           // 8B chunks of DwT pad
        int bn = g / 88, off = g - bn * 88;
        *(uint2*)(DwT + (size_t)(bn * HPAD + HDIM) * 16 + off * 4) = make_uint2(0u, 0u);
    }
}

// ---------------------------------------------------------------------------
// k_lt1 (grid 1056): two independent GEMMs, XCD-affinity swizzled + reg
// prefetch.
//  [0,704):    logits 64x64 tiles (split-bf16 3-product) + fused Dw softmax.
//              xcd=bid&7, slot=bid>>3, rt=slot&3, ct=(slot>>2)*8+xcd
//              (4 rt-siblings of one ct share an XCD -> phi L2 reuse)
//  [704,1056): T1b = xh * W1^T, 128x64 tiles.
//              xcd, slot=..., rh=slot&1, ct=(slot>>1)*8+xcd (2 rh-siblings)
// ---------------------------------------------------------------------------
__global__ __launch_bounds__(256) void k_lt1(
    const u16* __restrict__ xh, const u16* __restrict__ xl,
    const float* __restrict__ phi, const float* __restrict__ W1,
    float* __restrict__ logits, u16* __restrict__ DwT, u16* __restrict__ T1b) {
    __shared__ __align__(16) char SMEM[29184];
    const int bid = blockIdx.x, tid = threadIdx.x;
    const int wv = tid >> 6, lane = tid & 63, quad = lane >> 4, l15 = lane & 15;
    if (bid < 704) {
        const int xcd = bid & 7, slot = bid >> 3;
        const int rt = slot & 3, ct = (slot >> 2) * 8 + xcd;
        if (ct >= 171) return;                     // 20 hole blocks
        u16* AH = (u16*)SMEM;                // 64*40
        u16* AL = (u16*)(SMEM + 5120);
        u16* BH = (u16*)(SMEM + 10240);
        u16* BL = (u16*)(SMEM + 15360);
        float* F = (float*)(SMEM + 20480);   // 32*68
        const int r = tid >> 2, kg = (tid & 3) * 8;
        const u16* aph = xh + (size_t)(rt * 64 + r) * 512 + kg;
        const u16* apl = xl + (size_t)(rt * 64 + r) * 512 + kg;
        const int dl = tid >> 3, cg = (tid & 7) * 8;
        const int c0 = ct * 64 + cg;
        float vB[8];
        auto loadB = [&](int kb) {
            const float* src = phi + (size_t)(kb + dl) * NHCOL + c0;
            if (c0 + 8 <= NHCOL) {
                *(float4*)&vB[0] = *(const float4*)&src[0];
                *(float4*)&vB[4] = *(const float4*)&src[4];
            } else {
                #pragma unroll
                for (int i = 0; i < 8; ++i) vB[i] = (c0 + i < NHCOL) ? src[i] : 0.f;
            }
        };
        uint4 rAh = *(const uint4*)aph;
        uint4 rAl = *(const uint4*)apl;
        loadB(0);
        f32x4 acc[4] = {};
        for (int kb = 0; kb < 512; kb += 32) {
            *(uint4*)&AH[r * 40 + kg] = rAh;
            *(uint4*)&AL[r * 40 + kg] = rAl;
            *(float4*)&F[dl * 68 + cg]     = *(float4*)&vB[0];
            *(float4*)&F[dl * 68 + cg + 4] = *(float4*)&vB[4];
            __syncthreads();
            if (kb + 32 < 512) {                    // prefetch next K-step
                rAh = *(const uint4*)(aph + kb + 32);
                rAl = *(const uint4*)(apl + kb + 32);
                loadB(kb + 32);
            }
            { // transpose + hi/lo split
                int cc = tid & 63, q = tid >> 6;
                u16 th[8], tl[8];
                #pragma unroll
                for (int i = 0; i < 8; ++i) {
                    float v = F[(q * 8 + i) * 68 + cc];
                    th[i] = f2bf(v);
                    tl[i] = f2bf(v - bf2f(th[i]));
                }
                *(uint4*)&BH[cc * 40 + q * 8] = *(uint4*)&th[0];
                *(uint4*)&BL[cc * 40 + q * 8] = *(uint4*)&tl[0];
            }
            __syncthreads();
            bf16x8 ah = *(const bf16x8*)&AH[(wv * 16 + l15) * 40 + quad * 8];
            bf16x8 al = *(const bf16x8*)&AL[(wv * 16 + l15) * 40 + quad * 8];
            #pragma unroll
            for (int j = 0; j < 4; ++j) {
                bf16x8 bh = *(const bf16x8*)&BH[(j * 16 + l15) * 40 + quad * 8];
                bf16x8 bl = *(const bf16x8*)&BL[(j * 16 + l15) * 40 + quad * 8];
                acc[j] = __builtin_amdgcn_mfma_f32_16x16x32_bf16(ah, bh, acc[j], 0, 0, 0);
                acc[j] = __builtin_amdgcn_mfma_f32_16x16x32_bf16(ah, bl, acc[j], 0, 0, 0);
                acc[j] = __builtin_amdgcn_mfma_f32_16x16x32_bf16(al, bh, acc[j], 0, 0, 0);
            }
            __syncthreads();
        }
        // epilogue: logits + fused Dw softmax over m
        const int b  = rt * 4 + wv;
        const int r0 = rt * 64 + wv * 16 + quad * 4;
        #pragma unroll
        for (int j = 0; j < 4; ++j) {
            const int col = ct * 64 + j * 16 + l15;
            float a0 = acc[j][0], a1 = acc[j][1], a2 = acc[j][2], a3 = acc[j][3];
            if (col < NHCOL) {
                logits[(size_t)(r0 + 0) * NHCOL + col] = a0;
                logits[(size_t)(r0 + 1) * NHCOL + col] = a1;
                logits[(size_t)(r0 + 2) * NHCOL + col] = a2;
                logits[(size_t)(r0 + 3) * NHCOL + col] = a3;
            }
            float mx = fmaxf(fmaxf(a0, a1), fmaxf(a2, a3));
            mx = fmaxf(mx, __shfl_xor(mx, 16));
            mx = fmaxf(mx, __shfl_xor(mx, 32));
            float e0 = expf(a0 - mx), e1 = expf(a1 - mx);
            float e2 = expf(a2 - mx), e3 = expf(a3 - mx);
            float s = e0 + e1 + e2 + e3;
            s += __shfl_xor(s, 16);
            s += __shfl_xor(s, 32);
            float inv = 1.f / s;
            if (col < NHCOL) {
                int n = col / HDIM;
                int p2 = col - n * HDIM;
                u16* dst = DwT + ((size_t)((b * 16 + n) * HPAD + p2)) * 16 + quad * 4;
                *(uint2*)dst = make_uint2(pk2bf(e0 * inv, e1 * inv), pk2bf(e2 * inv, e3 * inv));
            }
        }
    } else {
        // T1: 128x64 tile, in-kernel W1 transpose, XCD-grouped rh-siblings
        const int b2_ = bid - 704;
        const int xcd = b2_ & 7, slot = b2_ >> 3;
        const int rh = slot & 1, ct = (slot >> 1) * 8 + xcd;   // 0..175 exact
        const int n = ct / 11, h0 = (ct % 11) * 64;
        u16* As = (u16*)SMEM;                  // 128*40
        u16* Bs = (u16*)(SMEM + 10240);        //  64*40
        float* F = (float*)(SMEM + 15360);     //  32*68
        const int r = tid >> 1, kg = (tid & 1) * 16;
        const u16* ap = xh + (size_t)(rh * 128 + r) * 512 + kg;
        const int dl = tid >> 3, cg = (tid & 7) * 8;
        const int h = h0 + cg;
        float vB[8];
        auto loadB = [&](int kb) {
            const float* wr = W1 + ((size_t)n * 512 + kb + dl) * HDIM + h;
            if (h + 8 <= HDIM) {
                #pragma unroll
                for (int i = 0; i < 4; ++i) {
                    float2 t = *(const float2*)&wr[i * 2];
                    vB[i * 2] = t.x; vB[i * 2 + 1] = t.y;
                }
            } else {
                #pragma unroll
                for (int i = 0; i < 8; ++i) vB[i] = (h + i < HDIM) ? wr[i] : 0.f;
            }
        };
        uint4 rA0 = *(const uint4*)ap;
        uint4 rA1 = *(const uint4*)(ap + 8);
        loadB(0);
        f32x4 acc[2][4] = {};
        for (int kb = 0; kb < 512; kb += 32) {
            *(uint4*)&As[r * 40 + kg]     = rA0;
            *(uint4*)&As[r * 40 + kg + 8] = rA1;
            *(float4*)&F[dl * 68 + cg]     = *(float4*)&vB[0];
            *(float4*)&F[dl * 68 + cg + 4] = *(float4*)&vB[4];
            __syncthreads();
            if (kb + 32 < 512) {                    // prefetch next K-step
                rA0 = *(const uint4*)(ap + kb + 32);
                rA1 = *(const uint4*)(ap + kb + 40);
                loadB(kb + 32);
            }
            { // transpose + cvt
                int cc = tid & 63, q = tid >> 6;
                u16 tv[8];
                #pragma unroll
                for (int i = 0; i < 8; ++i) tv[i] = f2bf(F[(q * 8 + i) * 68 + cc]);
                *(uint4*)&Bs[cc * 40 + q * 8] = *(uint4*)&tv[0];
            }
            __syncthreads();
            bf16x8 af[2], bfr[4];
            #pragma unroll
            for (int i = 0; i < 2; ++i)
                af[i] = *(const bf16x8*)&As[(wv * 32 + i * 16 + l15) * 40 + quad * 8];
            #pragma unroll
            for (int j = 0; j < 4; ++j)
                bfr[j] = *(const bf16x8*)&Bs[(j * 16 + l15) * 40 + quad * 8];
            #pragma unroll
            for (int i = 0; i < 2; ++i)
                #pragma unroll
                for (int j = 0; j < 4; ++j)
                    acc[i][j] = __builtin_amdgcn_mfma_f32_16x16x32_bf16(af[i], bfr[j], acc[i][j], 0, 0, 0);
            __syncthreads();
        }
        #pragma unroll
        for (int i = 0; i < 2; ++i)
            #pragma unroll
            for (int j = 0; j < 4; ++j) {
                int col = ct * 64 + j * 16 + l15;   // padded col = n*704+h
                int r0  = rh * 128 + wv * 32 + i * 16 + quad * 4;
                #pragma unroll
                for (int rr = 0; rr < 4; ++rr)
                    T1b[(size_t)(r0 + rr) * NHPCOL + col] = f2bf(acc[i][j][rr]);
            }
    }
}

// ---------------------------------------------------------------------------
// k_cw (grid 256 x 512 threads): Cw = softmax_p(softmax_n(logits)) -> CwB
// 512 threads raises per-CU wave count (1 block/CU) to 8 waves.
// ---------------------------------------------------------------------------
__global__ __launch_bounds__(512) void k_cw(
    const float* __restrict__ L, u16* __restrict__ CwB) {
    __shared__ __align__(16) float row[NHCOL];
    const int bid = blockIdx.x, tid = threadIdx.x;
    const int m = bid & 15, b = bid >> 4;
    const float* Lrow = L + (size_t)(b * 16 + m) * NHCOL;
    for (int i4 = tid; i4 < NHCOL / 4; i4 += 512)
        *(float4*)&row[i4 * 4] = *(const float4*)&Lrow[i4 * 4];
    __syncthreads();
    for (int p = tid; p < HDIM; p += 512) {
        float v[16];
        float mx = -1e30f;
        #pragma unroll
        for (int n = 0; n < 16; ++n) { v[n] = row[n * HDIM + p]; mx = fmaxf(mx, v[n]); }
        float s = 0.f;
        #pragma unroll
        for (int n = 0; n < 16; ++n) { v[n] = expf(v[n] - mx); s += v[n]; }
        float inv = 1.f / s;
        #pragma unroll
        for (int n = 0; n < 16; ++n) row[n * HDIM + p] = expf(v[n] * inv);  // cache exp(s1)
    }
    __syncthreads();
    const int wv = tid >> 6, lane = tid & 63;
    for (int nn = 0; nn < 2; ++nn) {
        int n = wv * 2 + nn;
        float s = 0.f;
        for (int p = lane; p < HDIM; p += 64) s += row[n * HDIM + p];
        #pragma unroll
        for (int off = 32; off > 0; off >>= 1) s += __shfl_xor(s, off);
        float inv = 1.f / s;
        u16* dst = CwB + (size_t)(((b * 16 + n) * 16 + m)) * HPAD;
        for (int p = lane; p < HDIM; p += 64) dst[p] = f2bf(row[n * HDIM + p] * inv);
        if (lane < HPAD - HDIM) dst[HDIM + lane] = 0;
    }
}

// ---------------------------------------------------------------------------
// Fused middle (grid 1536 flat, XCD-grouped: 6 ht-siblings of one (b,n)
// share an XCD for DwT/CwB L2 reuse):
//  stage1: hmid = relu(b1 + Dw^T·T1) via 32x32x16; stage2: G += Cw·hmid
// ---------------------------------------------------------------------------
__global__ __launch_bounds__(256) void k_mid(
    const u16* __restrict__ T1b, const u16* __restrict__ DwT,
    const u16* __restrict__ CwB, const float* __restrict__ b1,
    u16* __restrict__ Gb) {
    __shared__ u16 T1T[128 * 24];
    __shared__ u16 hmidT[128 * 64];
    const int bid = blockIdx.x;
    const int xcd = bid & 7, slot = bid >> 3;
    const int ht = slot % 6, gg = slot / 6;
    const int g = gg * 8 + xcd;
    const int n = g & 15, b = g >> 4;
    const int tid = threadIdx.x;
    const int wv = tid >> 6, lane = tid & 63;
    const int quad = lane >> 4, l15 = lane & 15;
    const int l31 = lane & 31, half = lane >> 5;
    const int h0 = ht * 128;
    const int b16n = b * 16 + n;

    {
        int m = tid & 15, hh0 = (tid >> 4) * 8;
        u16 v[8];
        if (h0 + hh0 + 8 <= HPAD) {
            *(uint4*)v = *(const uint4*)(T1b + (size_t)(b * 16 + m) * NHPCOL + n * HPAD + h0 + hh0);
        } else {
            #pragma unroll
            for (int i = 0; i < 8; ++i) v[i] = 0;
        }
        #pragma unroll
        for (int i = 0; i < 8; ++i) T1T[(hh0 + i) * 24 + m] = v[i];
    }
    __syncthreads();

    const int hrow = wv * 32 + l31;
    bf16x8 bt1 = *(const bf16x8*)&T1T[hrow * 24 + half * 8];
    int hg1 = h0 + hrow;
    float biasf = (hg1 < HDIM) ? b1[n * HDIM + hg1] : 0.f;
    f32x16 cbias;
    #pragma unroll
    for (int i = 0; i < 16; ++i) cbias[i] = biasf;

    const u16* dwbase = DwT + (size_t)(b16n * HPAD) * 16;
    const u16* cwrow  = CwB + (size_t)(b16n * 16 + l15) * HPAD;

    f32x4 acc[2] = {};
    const int hsw = hrow & 7;
    for (int c = 0; c < 11; ++c) {
        const int p0 = c * 64;
        #pragma unroll
        for (int pt = 0; pt < 2; ++pt) {
            bf16x8 adw = *(const bf16x8*)(dwbase + (size_t)(p0 + pt * 32 + l31) * 16 + half * 8);
            f32x16 hm = __builtin_amdgcn_mfma_f32_32x32x16_bf16(adw, bt1, cbias, 0, 0, 0);
            #pragma unroll
            for (int g2 = 0; g2 < 4; ++g2) {
                float v0 = fmaxf(hm[g2 * 4 + 0], 0.f);
                float v1 = fmaxf(hm[g2 * 4 + 1], 0.f);
                float v2 = fmaxf(hm[g2 * 4 + 2], 0.f);
                float v3 = fmaxf(hm[g2 * 4 + 3], 0.f);
                uint2 pk = make_uint2(pk2bf(v0, v1), pk2bf(v2, v3));
                int gran = (pt * 4 + g2) ^ hsw;
                *(uint2*)&hmidT[hrow * 64 + gran * 8 + half * 4] = pk;
            }
        }
        #pragma unroll
        for (int s = 0; s < 2; ++s) {
            bf16x8 acw = *(const bf16x8*)(cwrow + p0 + s * 32 + quad * 8);
            #pragma unroll
            for (int hj = 0; hj < 2; ++hj) {
                int hr = wv * 32 + hj * 16 + l15;
                int gr = (s * 4 + quad) ^ (hr & 7);
                bf16x8 bh = *(const bf16x8*)&hmidT[hr * 64 + gr * 8];
                acc[hj] = __builtin_amdgcn_mfma_f32_16x16x32_bf16(acw, bh, acc[hj], 0, 0, 0);
            }
        }
    }
    #pragma unroll
    for (int hj = 0; hj < 2; ++hj) {
        int h = h0 + wv * 32 + hj * 16 + l15;
        if (h < HPAD) {
            #pragma unroll
            for (int r = 0; r < 4; ++r) {
                int m = quad * 4 + r;
                Gb[(size_t)(b * 16 + m) * NHPCOL + n * HPAD + h] = f2bf(acc[hj][r]);
            }
        }
    }
}

// ---------------------------------------------------------------------------
// MFMA split-K GEMM with in-kernel W2 transpose + reg prefetch.
// Y[256][512] += Gb[.., n-slice] * W2[n]^T.  grid 512 flat, XCD-grouped:
// 4 rt-siblings of one (ct,nz) share an XCD (W2 panel L2 reuse).
// ---------------------------------------------------------------------------
__global__ __launch_bounds__(256) void k_ygemm(
    const u16* __restrict__ G, const float* __restrict__ W2, float* __restrict__ Y) {
    __shared__ u16 AsL[64 * 40];
    __shared__ u16 BsL[128 * 40];
    __shared__ float F[32 * 132];
    const int bid = blockIdx.x;
    const int xcd = bid & 7, slot = bid >> 3;
    const int rt = slot & 3, gg = slot >> 2;
    const int g = gg * 8 + xcd;
    const int ct = g & 3, nz = g >> 2;
    const int n = nz >> 1, kb0 = (nz & 1) * 352;
    const int tid = threadIdx.x;
    const int wv = tid >> 6, lane = tid & 63, quad = lane >> 4, l15 = lane & 15;
    const int m0 = rt * 64, d0 = ct * 128;
    const int am = tid >> 2, akg = (tid & 3) * 8;
    const u16* apg = G + (size_t)(m0 + am) * NHPCOL + n * HPAD + akg;
    const int hl = tid >> 3, cg = (tid & 7) * 16;
    float vB[16];
    auto loadB = [&](int kb) {
        int h = kb + hl;
        if (h < HDIM) {
            const float* src = W2 + ((size_t)n * HDIM + h) * 512 + d0 + cg;
            *(float4*)&vB[0]  = *(const float4*)&src[0];
            *(float4*)&vB[4]  = *(const float4*)&src[4];
            *(float4*)&vB[8]  = *(const float4*)&src[8];
            *(float4*)&vB[12] = *(const float4*)&src[12];
        } else {
            #pragma unroll
            for (int i = 0; i < 16; ++i) vB[i] = 0.f;
        }
    };
    uint4 rA = *(const uint4*)(apg + kb0);
    loadB(kb0);
    f32x4 acc[4][2] = {};
    for (int kb = kb0; kb < kb0 + 352; kb += 32) {
        *(uint4*)&AsL[am * 40 + akg] = rA;
        *(float4*)&F[hl * 132 + cg]      = *(float4*)&vB[0];
        *(float4*)&F[hl * 132 + cg + 4]  = *(float4*)&vB[4];
        *(float4*)&F[hl * 132 + cg + 8]  = *(float4*)&vB[8];
        *(float4*)&F[hl * 132 + cg + 12] = *(float4*)&vB[12];
        __syncthreads();
        if (kb + 32 < kb0 + 352) {                  // prefetch next K-step
            rA = *(const uint4*)(apg + kb + 32);
            loadB(kb + 32);
        }
        { // transpose + cvt -> BsL[d][k]
            int cc = tid & 127, half = tid >> 7;
            u16 tv[16];
            #pragma unroll
            for (int i = 0; i < 16; ++i) tv[i] = f2bf(F[(half * 16 + i) * 132 + cc]);
            *(uint4*)&BsL[cc * 40 + half * 16]     = *(uint4*)&tv[0];
            *(uint4*)&BsL[cc * 40 + half * 16 + 8] = *(uint4*)&tv[8];
        }
        __syncthreads();
        bf16x8 af[4], bfr[2];
        #pragma unroll
        for (int i = 0; i < 4; ++i) af[i] = *(const bf16x8*)&AsL[(i * 16 + l15) * 40 + quad * 8];
        #pragma unroll
        for (int j = 0; j < 2; ++j) bfr[j] = *(const bf16x8*)&BsL[(wv * 32 + j * 16 + l15) * 40 + quad * 8];
        #pragma unroll
        for (int i = 0; i < 4; ++i)
            #pragma unroll
            for (int j = 0; j < 2; ++j)
                acc[i][j] = __builtin_amdgcn_mfma_f32_16x16x32_bf16(af[i], bfr[j], acc[i][j], 0, 0, 0);
        __syncthreads();
    }
    #pragma unroll
    for (int i = 0; i < 4; ++i)
        #pragma unroll
        for (int j = 0; j < 2; ++j) {
            int dcol = d0 + wv * 32 + j * 16 + l15;
            int r0 = m0 + i * 16 + quad * 4;
            #pragma unroll
            for (int r = 0; r < 4; ++r)
                atomicAdd(&Y[(size_t)(r0 + r) * 512 + dcol], acc[i][j][r]);
        }
}

// ---------------------------------------------------------------------------
// k_outgemm: out[16][512] += Yflat[16][k-slice] * Wout^T.  grid (ct=4, ks=128)
// 64-wide slices, in-kernel Wout transpose.
// ---------------------------------------------------------------------------
__global__ __launch_bounds__(256) void k_outgemm(
    const float* __restrict__ Y, const float* __restrict__ Wout, float* __restrict__ out) {
    __shared__ u16 AsL[16 * 40];
    __shared__ u16 BsL[128 * 40];
    __shared__ float F[32 * 132];
    const int ct = blockIdx.x, ks = blockIdx.y;
    const int tid = threadIdx.x;
    const int wv = tid >> 6, lane = tid & 63, quad = lane >> 4, l15 = lane & 15;
    const int o0 = ct * 128, kbase = ks * 64;
    f32x4 acc[2] = {};
    for (int kb = 0; kb < 64; kb += 32) {
        { // A staging from Y fp32
            int r = tid >> 4, k2 = (tid & 15) * 2;
            float2 v = *(const float2*)&Y[(size_t)r * 8192 + kbase + kb + k2];
            AsL[r * 40 + k2]     = f2bf(v.x);
            AsL[r * 40 + k2 + 1] = f2bf(v.y);
        }
        { // B step1: Wout fp32 -> F
            int kl = tid >> 3, cg = (tid & 7) * 16;
            const float* src = Wout + (size_t)(kbase + kb + kl) * 512 + o0 + cg;
            float v[16];
            *(float4*)&v[0]  = *(const float4*)&src[0];
            *(float4*)&v[4]  = *(const float4*)&src[4];
            *(float4*)&v[8]  = *(const float4*)&src[8];
            *(float4*)&v[12] = *(const float4*)&src[12];
            #pragma unroll
            for (int i = 0; i < 16; ++i) F[kl * 132 + cg + i] = v[i];
        }
        __syncthreads();
        { // B step2: transpose + cvt
            int cc = tid & 127, half = tid >> 7;
            u16 tv[16];
            #pragma unroll
            for (int i = 0; i < 16; ++i) tv[i] = f2bf(F[(half * 16 + i) * 132 + cc]);
            *(uint4*)&BsL[cc * 40 + half * 16]     = *(uint4*)&tv[0];
            *(uint4*)&BsL[cc * 40 + half * 16 + 8] = *(uint4*)&tv[8];
        }
        __syncthreads();
        bf16x8 af = *(const bf16x8*)&AsL[l15 * 40 + quad * 8];
        #pragma unroll
        for (int j = 0; j < 2; ++j) {
            bf16x8 bfr = *(const bf16x8*)&BsL[(wv * 32 + j * 16 + l15) * 40 + quad * 8];
            acc[j] = __builtin_amdgcn_mfma_f32_16x16x32_bf16(af, bfr, acc[j], 0, 0, 0);
        }
        __syncthreads();
    }
    #pragma unroll
    for (int j = 0; j < 2; ++j) {
        int o = o0 + wv * 32 + j * 16 + l15;
        #pragma unroll
        for (int r = 0; r < 4; ++r)
            atomicAdd(&out[(size_t)(quad * 4 + r) * 512 + o], acc[j][r]);
    }
}

// ---------------------------------------------------------------------------
extern "C" void kernel_launch(void* const* d_in, const int* in_sizes, int n_in,
                              void* d_out, int out_size, void* d_ws, size_t ws_size,
                              hipStream_t stream) {
    const float* x    = (const float*)d_in[0];
    const float* phi  = (const float*)d_in[1];
    const float* W1   = (const float*)d_in[2];
    const float* b1   = (const float*)d_in[3];
    const float* W2   = (const float*)d_in[4];
    const float* b2   = (const float*)d_in[5];
    const float* Wout = (const float*)d_in[6];
    const float* bout = (const float*)d_in[7];
    float* out = (float*)d_out;

    // Workspace (~35.3 MB)
    char* base = (char*)d_ws;
    float* logits = (float*)(base + 0);           // 11,173,888
    u16*   DwT    = (u16*)(base + 11173888);      //  5,767,168
    u16*   CwB    = (u16*)(base + 16941056);      //  5,767,168
    u16*   T1b    = (u16*)(base + 22708224);      //  5,767,168
    u16*   Gb     = (u16*)(base + 28475392);      //  5,767,168
    u16*   xh     = (u16*)(base + 34242560);      //    262,144
    u16*   xl     = (u16*)(base + 34504704);      //    262,144
    float* Y      = (float*)(base + 34766848);    //    524,288

    k_prep    <<<dim3(760), 256, 0, stream>>>(x, b2, bout, xh, xl, Y, out, DwT);
    k_lt1     <<<dim3(1056), 256, 0, stream>>>(xh, xl, phi, W1, logits, DwT, T1b);
    k_cw      <<<dim3(256), 512, 0, stream>>>(logits, CwB);
    k_mid     <<<dim3(1536), 256, 0, stream>>>(T1b, DwT, CwB, b1, Gb);
    k_ygemm   <<<dim3(512), 256, 0, stream>>>(Gb, W2, Y);
    k_outgemm <<<dim3(4, 128), 256, 0, stream>>>(Y, Wout, out);
}

// Round 10
// 209.047 us; speedup vs baseline: 1.1829x; 1.0023x over previous
//
#include <hip/hip_runtime.h>
#include <hip/hip_bf16.h>
#include <math.h>

typedef unsigned int   u32;
typedef unsigned short u16;
typedef __bf16 bf16;
typedef bf16  bf16x8  __attribute__((ext_vector_type(8)));
typedef float f32x4   __attribute__((ext_vector_type(4)));
typedef float f32x16  __attribute__((ext_vector_type(16)));

#define BBATCH 16
#define MTOK   16
#define NEXP   16
#define DDIM   512
#define HDIM   682
#define HPAD   704            // 11*64
#define NHCOL  (NEXP*HDIM)    // 10912
#define NHPCOL (NEXP*HPAD)    // 11264

__device__ __forceinline__ u16 f2bf(float f) {
    u32 u = __builtin_bit_cast(u32, f);
    u += 0x7fffu + ((u >> 16) & 1u);
    return (u16)(u >> 16);
}
__device__ __forceinline__ float bf2f(u16 h) {
    u32 u = ((u32)h) << 16;
    return __builtin_bit_cast(float, u);
}
__device__ __forceinline__ u32 pk2bf(float a, float b) {
    __hip_bfloat162 t = __float22bfloat162_rn(float2{a, b});
    u32 r;
    __builtin_memcpy(&r, &t, 4);
    return r;
}

// ---------------------------------------------------------------------------
// k_prep (grid 128): ONLY the x -> xh/xl bf16 split (gates k_lt1).
// All other init work moved to later, underutilized dispatches.
// ---------------------------------------------------------------------------
__global__ __launch_bounds__(256) void k_prep(
    const float* __restrict__ x,
    u16* __restrict__ xh, u16* __restrict__ xl) {
    const int bid = blockIdx.x, tid = threadIdx.x;
    int i = (bid * 256 + tid) * 4;
    float4 v = *(const float4*)&x[i];
    float a[4] = {v.x, v.y, v.z, v.w};
    u16 hh[4], ll[4];
    #pragma unroll
    for (int j = 0; j < 4; ++j) {
        hh[j] = f2bf(a[j]);
        ll[j] = f2bf(a[j] - bf2f(hh[j]));
    }
    *(uint2*)&xh[i] = make_uint2((u32)hh[0] | ((u32)hh[1] << 16), (u32)hh[2] | ((u32)hh[3] << 16));
    *(uint2*)&xl[i] = make_uint2((u32)ll[0] | ((u32)ll[1] << 16), (u32)ll[2] | ((u32)ll[3] << 16));
}

// ---------------------------------------------------------------------------
// k_lt1 (grid 1056): two independent GEMMs, XCD-affinity swizzled + reg
// prefetch.
//  [0,704):    logits 64x64 tiles (split-bf16 3-product) + fused Dw softmax.
//              xcd=bid&7, slot=bid>>3, rt=slot&3, ct=(slot>>2)*8+xcd
//              (4 rt-siblings of one ct share an XCD -> phi L2 reuse)
//              20 hole blocks (ct>=171) zero the DwT pad region instead.
//  [704,1056): T1b = xh * W1^T, 128x64 tiles.
// ---------------------------------------------------------------------------
__global__ __launch_bounds__(256) void k_lt1(
    const u16* __restrict__ xh, const u16* __restrict__ xl,
    const float* __restrict__ phi, const float* __restrict__ W1,
    float* __restrict__ logits, u16* __restrict__ DwT, u16* __restrict__ T1b) {
    __shared__ __align__(16) char SMEM[29184];
    const int bid = blockIdx.x, tid = threadIdx.x;
    const int wv = tid >> 6, lane = tid & 63, quad = lane >> 4, l15 = lane & 15;
    if (bid < 704) {
        const int xcd = bid & 7, slot = bid >> 3;
        const int rt = slot & 3, ct = (slot >> 2) * 8 + xcd;
        if (ct >= 171) {
            // idle hole blocks zero DwT pad (p in [682,704), disjoint from
            // the Dw-softmax writes in this dispatch; consumed by k_mid)
            const int hole = (slot & 3) * 5 + (xcd - 3);   // 0..19
            for (int g = hole * 256 + tid; g < 22528; g += 5120) {
                int bn = g / 88, off = g - bn * 88;
                *(uint2*)(DwT + (size_t)(bn * HPAD + HDIM) * 16 + off * 4) =
                    make_uint2(0u, 0u);
            }
            return;
        }
        u16* AH = (u16*)SMEM;                // 64*40
        u16* AL = (u16*)(SMEM + 5120);
        u16* BH = (u16*)(SMEM + 10240);
        u16* BL = (u16*)(SMEM + 15360);
        float* F = (float*)(SMEM + 20480);   // 32*68
        const int r = tid >> 2, kg = (tid & 3) * 8;
        const u16* aph = xh + (size_t)(rt * 64 + r) * 512 + kg;
        const u16* apl = xl + (size_t)(rt * 64 + r) * 512 + kg;
        const int dl = tid >> 3, cg = (tid & 7) * 8;
        const int c0 = ct * 64 + cg;
        float vB[8];
        auto loadB = [&](int kb) {
            const float* src = phi + (size_t)(kb + dl) * NHCOL + c0;
            if (c0 + 8 <= NHCOL) {
                *(float4*)&vB[0] = *(const float4*)&src[0];
                *(float4*)&vB[4] = *(const float4*)&src[4];
            } else {
                #pragma unroll
                for (int i = 0; i < 8; ++i) vB[i] = (c0 + i < NHCOL) ? src[i] : 0.f;
            }
        };
        uint4 rAh = *(const uint4*)aph;
        uint4 rAl = *(const uint4*)apl;
        loadB(0);
        f32x4 acc[4] = {};
        for (int kb = 0; kb < 512; kb += 32) {
            *(uint4*)&AH[r * 40 + kg] = rAh;
            *(uint4*)&AL[r * 40 + kg] = rAl;
            *(float4*)&F[dl * 68 + cg]     = *(float4*)&vB[0];
            *(float4*)&F[dl * 68 + cg + 4] = *(float4*)&vB[4];
            __syncthreads();
            if (kb + 32 < 512) {                    // prefetch next K-step
                rAh = *(const uint4*)(aph + kb + 32);
                rAl = *(const uint4*)(apl + kb + 32);
                loadB(kb + 32);
            }
            { // transpose + hi/lo split
                int cc = tid & 63, q = tid >> 6;
                u16 th[8], tl[8];
                #pragma unroll
                for (int i = 0; i < 8; ++i) {
                    float v = F[(q * 8 + i) * 68 + cc];
                    th[i] = f2bf(v);
                    tl[i] = f2bf(v - bf2f(th[i]));
                }
                *(uint4*)&BH[cc * 40 + q * 8] = *(uint4*)&th[0];
                *(uint4*)&BL[cc * 40 + q * 8] = *(uint4*)&tl[0];
            }
            __syncthreads();
            bf16x8 ah = *(const bf16x8*)&AH[(wv * 16 + l15) * 40 + quad * 8];
            bf16x8 al = *(const bf16x8*)&AL[(wv * 16 + l15) * 40 + quad * 8];
            #pragma unroll
            for (int j = 0; j < 4; ++j) {
                bf16x8 bh = *(const bf16x8*)&BH[(j * 16 + l15) * 40 + quad * 8];
                bf16x8 bl = *(const bf16x8*)&BL[(j * 16 + l15) * 40 + quad * 8];
                acc[j] = __builtin_amdgcn_mfma_f32_16x16x32_bf16(ah, bh, acc[j], 0, 0, 0);
                acc[j] = __builtin_amdgcn_mfma_f32_16x16x32_bf16(ah, bl, acc[j], 0, 0, 0);
                acc[j] = __builtin_amdgcn_mfma_f32_16x16x32_bf16(al, bh, acc[j], 0, 0, 0);
            }
            __syncthreads();
        }
        // epilogue: logits + fused Dw softmax over m
        const int b  = rt * 4 + wv;
        const int r0 = rt * 64 + wv * 16 + quad * 4;
        #pragma unroll
        for (int j = 0; j < 4; ++j) {
            const int col = ct * 64 + j * 16 + l15;
            float a0 = acc[j][0], a1 = acc[j][1], a2 = acc[j][2], a3 = acc[j][3];
            if (col < NHCOL) {
                logits[(size_t)(r0 + 0) * NHCOL + col] = a0;
                logits[(size_t)(r0 + 1) * NHCOL + col] = a1;
                logits[(size_t)(r0 + 2) * NHCOL + col] = a2;
                logits[(size_t)(r0 + 3) * NHCOL + col] = a3;
            }
            float mx = fmaxf(fmaxf(a0, a1), fmaxf(a2, a3));
            mx = fmaxf(mx, __shfl_xor(mx, 16));
            mx = fmaxf(mx, __shfl_xor(mx, 32));
            float e0 = expf(a0 - mx), e1 = expf(a1 - mx);
            float e2 = expf(a2 - mx), e3 = expf(a3 - mx);
            float s = e0 + e1 + e2 + e3;
            s += __shfl_xor(s, 16);
            s += __shfl_xor(s, 32);
            float inv = 1.f / s;
            if (col < NHCOL) {
                int n = col / HDIM;
                int p2 = col - n * HDIM;
                u16* dst = DwT + ((size_t)((b * 16 + n) * HPAD + p2)) * 16 + quad * 4;
                *(uint2*)dst = make_uint2(pk2bf(e0 * inv, e1 * inv), pk2bf(e2 * inv, e3 * inv));
            }
        }
    } else {
        // T1: 128x64 tile, in-kernel W1 transpose, XCD-grouped rh-siblings
        const int b2_ = bid - 704;
        const int xcd = b2_ & 7, slot = b2_ >> 3;
        const int rh = slot & 1, ct = (slot >> 1) * 8 + xcd;   // 0..175 exact
        const int n = ct / 11, h0 = (ct % 11) * 64;
        u16* As = (u16*)SMEM;                  // 128*40
        u16* Bs = (u16*)(SMEM + 10240);        //  64*40
        float* F = (float*)(SMEM + 15360);     //  32*68
        const int r = tid >> 1, kg = (tid & 1) * 16;
        const u16* ap = xh + (size_t)(rh * 128 + r) * 512 + kg;
        const int dl = tid >> 3, cg = (tid & 7) * 8;
        const int h = h0 + cg;
        float vB[8];
        auto loadB = [&](int kb) {
            const float* wr = W1 + ((size_t)n * 512 + kb + dl) * HDIM + h;
            if (h + 8 <= HDIM) {
                #pragma unroll
                for (int i = 0; i < 4; ++i) {
                    float2 t = *(const float2*)&wr[i * 2];
                    vB[i * 2] = t.x; vB[i * 2 + 1] = t.y;
                }
            } else {
                #pragma unroll
                for (int i = 0; i < 8; ++i) vB[i] = (h + i < HDIM) ? wr[i] : 0.f;
            }
        };
        uint4 rA0 = *(const uint4*)ap;
        uint4 rA1 = *(const uint4*)(ap + 8);
        loadB(0);
        f32x4 acc[2][4] = {};
        for (int kb = 0; kb < 512; kb += 32) {
            *(uint4*)&As[r * 40 + kg]     = rA0;
            *(uint4*)&As[r * 40 + kg + 8] = rA1;
            *(float4*)&F[dl * 68 + cg]     = *(float4*)&vB[0];
            *(float4*)&F[dl * 68 + cg + 4] = *(float4*)&vB[4];
            __syncthreads();
            if (kb + 32 < 512) {                    // prefetch next K-step
                rA0 = *(const uint4*)(ap + kb + 32);
                rA1 = *(const uint4*)(ap + kb + 40);
                loadB(kb + 32);
            }
            { // transpose + cvt
                int cc = tid & 63, q = tid >> 6;
                u16 tv[8];
                #pragma unroll
                for (int i = 0; i < 8; ++i) tv[i] = f2bf(F[(q * 8 + i) * 68 + cc]);
                *(uint4*)&Bs[cc * 40 + q * 8] = *(uint4*)&tv[0];
            }
            __syncthreads();
            bf16x8 af[2], bfr[4];
            #pragma unroll
            for (int i = 0; i < 2; ++i)
                af[i] = *(const bf16x8*)&As[(wv * 32 + i * 16 + l15) * 40 + quad * 8];
            #pragma unroll
            for (int j = 0; j < 4; ++j)
                bfr[j] = *(const bf16x8*)&Bs[(j * 16 + l15) * 40 + quad * 8];
            #pragma unroll
            for (int i = 0; i < 2; ++i)
                #pragma unroll
                for (int j = 0; j < 4; ++j)
                    acc[i][j] = __builtin_amdgcn_mfma_f32_16x16x32_bf16(af[i], bfr[j], acc[i][j], 0, 0, 0);
            __syncthreads();
        }
        #pragma unroll
        for (int i = 0; i < 2; ++i)
            #pragma unroll
            for (int j = 0; j < 4; ++j) {
                int col = ct * 64 + j * 16 + l15;   // padded col = n*704+h
                int r0  = rh * 128 + wv * 32 + i * 16 + quad * 4;
                #pragma unroll
                for (int rr = 0; rr < 4; ++rr)
                    T1b[(size_t)(r0 + rr) * NHPCOL + col] = f2bf(acc[i][j][rr]);
            }
    }
}

// ---------------------------------------------------------------------------
// k_cw (grid 528 x 512 threads):
//  [0,256):   Cw = softmax_p(softmax_n(logits)) -> CwB
//  [256,512): Y init = sum_n b2 (consumed by k_ygemm, 2 dispatches later)
//  [512,528): out init = bout   (consumed by k_outgemm)
// ---------------------------------------------------------------------------
__global__ __launch_bounds__(512) void k_cw(
    const float* __restrict__ L, u16* __restrict__ CwB,
    const float* __restrict__ b2, const float* __restrict__ bout,
    float* __restrict__ Y, float* __restrict__ out) {
    __shared__ __align__(16) float row[NHCOL];
    const int bid = blockIdx.x, tid = threadIdx.x;
    if (bid >= 256) {
        if (bid < 512) {
            int idx = (bid - 256) * 512 + tid;
            int d = idx & 511;
            float s = 0.f;
            #pragma unroll
            for (int nn = 0; nn < 16; ++nn) s += b2[nn * 512 + d];
            Y[idx] = s;
        } else {
            int idx = (bid - 512) * 512 + tid;
            out[idx] = bout[idx & 511];
        }
        return;
    }
    const int m = bid & 15, b = bid >> 4;
    const float* Lrow = L + (size_t)(b * 16 + m) * NHCOL;
    for (int i4 = tid; i4 < NHCOL / 4; i4 += 512)
        *(float4*)&row[i4 * 4] = *(const float4*)&Lrow[i4 * 4];
    __syncthreads();
    for (int p = tid; p < HDIM; p += 512) {
        float v[16];
        float mx = -1e30f;
        #pragma unroll
        for (int n = 0; n < 16; ++n) { v[n] = row[n * HDIM + p]; mx = fmaxf(mx, v[n]); }
        float s = 0.f;
        #pragma unroll
        for (int n = 0; n < 16; ++n) { v[n] = expf(v[n] - mx); s += v[n]; }
        float inv = 1.f / s;
        #pragma unroll
        for (int n = 0; n < 16; ++n) row[n * HDIM + p] = expf(v[n] * inv);  // cache exp(s1)
    }
    __syncthreads();
    const int wv = tid >> 6, lane = tid & 63;
    for (int nn = 0; nn < 2; ++nn) {
        int n = wv * 2 + nn;
        float s = 0.f;
        for (int p = lane; p < HDIM; p += 64) s += row[n * HDIM + p];
        #pragma unroll
        for (int off = 32; off > 0; off >>= 1) s += __shfl_xor(s, off);
        float inv = 1.f / s;
        u16* dst = CwB + (size_t)(((b * 16 + n) * 16 + m)) * HPAD;
        for (int p = lane; p < HDIM; p += 64) dst[p] = f2bf(row[n * HDIM + p] * inv);
        if (lane < HPAD - HDIM) dst[HDIM + lane] = 0;
    }
}

// ---------------------------------------------------------------------------
// Fused middle (grid 1536 flat, XCD-grouped: 6 ht-siblings of one (b,n)
// share an XCD for DwT/CwB L2 reuse):
//  stage1: hmid = relu(b1 + Dw^T·T1) via 32x32x16; stage2: G += Cw·hmid
// ---------------------------------------------------------------------------
__global__ __launch_bounds__(256) void k_mid(
    const u16* __restrict__ T1b, const u16* __restrict__ DwT,
    const u16* __restrict__ CwB, const float* __restrict__ b1,
    u16* __restrict__ Gb) {
    __shared__ u16 T1T[128 * 24];
    __shared__ u16 hmidT[128 * 64];
    const int bid = blockIdx.x;
    const int xcd = bid & 7, slot = bid >> 3;
    const int ht = slot % 6, gg = slot / 6;
    const int g = gg * 8 + xcd;
    const int n = g & 15, b = g >> 4;
    const int tid = threadIdx.x;
    const int wv = tid >> 6, lane = tid & 63;
    const int quad = lane >> 4, l15 = lane & 15;
    const int l31 = lane & 31, half = lane >> 5;
    const int h0 = ht * 128;
    const int b16n = b * 16 + n;

    {
        int m = tid & 15, hh0 = (tid >> 4) * 8;
        u16 v[8];
        if (h0 + hh0 + 8 <= HPAD) {
            *(uint4*)v = *(const uint4*)(T1b + (size_t)(b * 16 + m) * NHPCOL + n * HPAD + h0 + hh0);
        } else {
            #pragma unroll
            for (int i = 0; i < 8; ++i) v[i] = 0;
        }
        #pragma unroll
        for (int i = 0; i < 8; ++i) T1T[(hh0 + i) * 24 + m] = v[i];
    }
    __syncthreads();

    const int hrow = wv * 32 + l31;
    bf16x8 bt1 = *(const bf16x8*)&T1T[hrow * 24 + half * 8];
    int hg1 = h0 + hrow;
    float biasf = (hg1 < HDIM) ? b1[n * HDIM + hg1] : 0.f;
    f32x16 cbias;
    #pragma unroll
    for (int i = 0; i < 16; ++i) cbias[i] = biasf;

    const u16* dwbase = DwT + (size_t)(b16n * HPAD) * 16;
    const u16* cwrow  = CwB + (size_t)(b16n * 16 + l15) * HPAD;

    f32x4 acc[2] = {};
    const int hsw = hrow & 7;
    for (int c = 0; c < 11; ++c) {
        const int p0 = c * 64;
        #pragma unroll
        for (int pt = 0; pt < 2; ++pt) {
            bf16x8 adw = *(const bf16x8*)(dwbase + (size_t)(p0 + pt * 32 + l31) * 16 + half * 8);
            f32x16 hm = __builtin_amdgcn_mfma_f32_32x32x16_bf16(adw, bt1, cbias, 0, 0, 0);
            #pragma unroll
            for (int g2 = 0; g2 < 4; ++g2) {
                float v0 = fmaxf(hm[g2 * 4 + 0], 0.f);
                float v1 = fmaxf(hm[g2 * 4 + 1], 0.f);
                float v2 = fmaxf(hm[g2 * 4 + 2], 0.f);
                float v3 = fmaxf(hm[g2 * 4 + 3], 0.f);
                uint2 pk = make_uint2(pk2bf(v0, v1), pk2bf(v2, v3));
                int gran = (pt * 4 + g2) ^ hsw;
                *(uint2*)&hmidT[hrow * 64 + gran * 8 + half * 4] = pk;
            }
        }
        #pragma unroll
        for (int s = 0; s < 2; ++s) {
            bf16x8 acw = *(const bf16x8*)(cwrow + p0 + s * 32 + quad * 8);
            #pragma unroll
            for (int hj = 0; hj < 2; ++hj) {
                int hr = wv * 32 + hj * 16 + l15;
                int gr = (s * 4 + quad) ^ (hr & 7);
                bf16x8 bh = *(const bf16x8*)&hmidT[hr * 64 + gr * 8];
                acc[hj] = __builtin_amdgcn_mfma_f32_16x16x32_bf16(acw, bh, acc[hj], 0, 0, 0);
            }
        }
    }
    #pragma unroll
    for (int hj = 0; hj < 2; ++hj) {
        int h = h0 + wv * 32 + hj * 16 + l15;
        if (h < HPAD) {
            #pragma unroll
            for (int r = 0; r < 4; ++r) {
                int m = quad * 4 + r;
                Gb[(size_t)(b * 16 + m) * NHPCOL + n * HPAD + h] = f2bf(acc[hj][r]);
            }
        }
    }
}

// ---------------------------------------------------------------------------
// MFMA split-K GEMM with in-kernel W2 transpose + reg prefetch.
// Y[256][512] += Gb[.., n-slice] * W2[n]^T.  grid 512 flat, XCD-grouped:
// 4 rt-siblings of one (ct,nz) share an XCD (W2 panel L2 reuse).
// ---------------------------------------------------------------------------
__global__ __launch_bounds__(256) void k_ygemm(
    const u16* __restrict__ G, const float* __restrict__ W2, float* __restrict__ Y) {
    __shared__ u16 AsL[64 * 40];
    __shared__ u16 BsL[128 * 40];
    __shared__ float F[32 * 132];
    const int bid = blockIdx.x;
    const int xcd = bid & 7, slot = bid >> 3;
    const int rt = slot & 3, gg = slot >> 2;
    const int g = gg * 8 + xcd;
    const int ct = g & 3, nz = g >> 2;
    const int n = nz >> 1, kb0 = (nz & 1) * 352;
    const int tid = threadIdx.x;
    const int wv = tid >> 6, lane = tid & 63, quad = lane >> 4, l15 = lane & 15;
    const int m0 = rt * 64, d0 = ct * 128;
    const int am = tid >> 2, akg = (tid & 3) * 8;
    const u16* apg = G + (size_t)(m0 + am) * NHPCOL + n * HPAD + akg;
    const int hl = tid >> 3, cg = (tid & 7) * 16;
    float vB[16];
    auto loadB = [&](int kb) {
        int h = kb + hl;
        if (h < HDIM) {
            const float* src = W2 + ((size_t)n * HDIM + h) * 512 + d0 + cg;
            *(float4*)&vB[0]  = *(const float4*)&src[0];
            *(float4*)&vB[4]  = *(const float4*)&src[4];
            *(float4*)&vB[8]  = *(const float4*)&src[8];
            *(float4*)&vB[12] = *(const float4*)&src[12];
        } else {
            #pragma unroll
            for (int i = 0; i < 16; ++i) vB[i] = 0.f;
        }
    };
    uint4 rA = *(const uint4*)(apg + kb0);
    loadB(kb0);
    f32x4 acc[4][2] = {};
    for (int kb = kb0; kb < kb0 + 352; kb += 32) {
        *(uint4*)&AsL[am * 40 + akg] = rA;
        *(float4*)&F[hl * 132 + cg]      = *(float4*)&vB[0];
        *(float4*)&F[hl * 132 + cg + 4]  = *(float4*)&vB[4];
        *(float4*)&F[hl * 132 + cg + 8]  = *(float4*)&vB[8];
        *(float4*)&F[hl * 132 + cg + 12] = *(float4*)&vB[12];
        __syncthreads();
        if (kb + 32 < kb0 + 352) {                  // prefetch next K-step
            rA = *(const uint4*)(apg + kb + 32);
            loadB(kb + 32);
        }
        { // transpose + cvt -> BsL[d][k]
            int cc = tid & 127, half = tid >> 7;
            u16 tv[16];
            #pragma unroll
            for (int i = 0; i < 16; ++i) tv[i] = f2bf(F[(half * 16 + i) * 132 + cc]);
            *(uint4*)&BsL[cc * 40 + half * 16]     = *(uint4*)&tv[0];
            *(uint4*)&BsL[cc * 40 + half * 16 + 8] = *(uint4*)&tv[8];
        }
        __syncthreads();
        bf16x8 af[4], bfr[2];
        #pragma unroll
        for (int i = 0; i < 4; ++i) af[i] = *(const bf16x8*)&AsL[(i * 16 + l15) * 40 + quad * 8];
        #pragma unroll
        for (int j = 0; j < 2; ++j) bfr[j] = *(const bf16x8*)&BsL[(wv * 32 + j * 16 + l15) * 40 + quad * 8];
        #pragma unroll
        for (int i = 0; i < 4; ++i)
            #pragma unroll
            for (int j = 0; j < 2; ++j)
                acc[i][j] = __builtin_amdgcn_mfma_f32_16x16x32_bf16(af[i], bfr[j], acc[i][j], 0, 0, 0);
        __syncthreads();
    }
    #pragma unroll
    for (int i = 0; i < 4; ++i)
        #pragma unroll
        for (int j = 0; j < 2; ++j) {
            int dcol = d0 + wv * 32 + j * 16 + l15;
            int r0 = m0 + i * 16 + quad * 4;
            #pragma unroll
            for (int r = 0; r < 4; ++r)
                atomicAdd(&Y[(size_t)(r0 + r) * 512 + dcol], acc[i][j][r]);
        }
}

// ---------------------------------------------------------------------------
// k_outgemm: out[16][512] += Yflat[16][k-slice] * Wout^T.  grid (ct=4, ks=128)
// 64-wide slices, in-kernel Wout transpose.
// ---------------------------------------------------------------------------
__global__ __launch_bounds__(256) void k_outgemm(
    const float* __restrict__ Y, const float* __restrict__ Wout, float* __restrict__ out) {
    __shared__ u16 AsL[16 * 40];
    __shared__ u16 BsL[128 * 40];
    __shared__ float F[32 * 132];
    const int ct = blockIdx.x, ks = blockIdx.y;
    const int tid = threadIdx.x;
    const int wv = tid >> 6, lane = tid & 63, quad = lane >> 4, l15 = lane & 15;
    const int o0 = ct * 128, kbase = ks * 64;
    f32x4 acc[2] = {};
    for (int kb = 0; kb < 64; kb += 32) {
        { // A staging from Y fp32
            int r = tid >> 4, k2 = (tid & 15) * 2;
            float2 v = *(const float2*)&Y[(size_t)r * 8192 + kbase + kb + k2];
            AsL[r * 40 + k2]     = f2bf(v.x);
            AsL[r * 40 + k2 + 1] = f2bf(v.y);
        }
        { // B step1: Wout fp32 -> F
            int kl = tid >> 3, cg = (tid & 7) * 16;
            const float* src = Wout + (size_t)(kbase + kb + kl) * 512 + o0 + cg;
            float v[16];
            *(float4*)&v[0]  = *(const float4*)&src[0];
            *(float4*)&v[4]  = *(const float4*)&src[4];
            *(float4*)&v[8]  = *(const float4*)&src[8];
            *(float4*)&v[12] = *(const float4*)&src[12];
            #pragma unroll
            for (int i = 0; i < 16; ++i) F[kl * 132 + cg + i] = v[i];
        }
        __syncthreads();
        { // B step2: transpose + cvt
            int cc = tid & 127, half = tid >> 7;
            u16 tv[16];
            #pragma unroll
            for (int i = 0; i < 16; ++i) tv[i] = f2bf(F[(half * 16 + i) * 132 + cc]);
            *(uint4*)&BsL[cc * 40 + half * 16]     = *(uint4*)&tv[0];
            *(uint4*)&BsL[cc * 40 + half * 16 + 8] = *(uint4*)&tv[8];
        }
        __syncthreads();
        bf16x8 af = *(const bf16x8*)&AsL[l15 * 40 + quad * 8];
        #pragma unroll
        for (int j = 0; j < 2; ++j) {
            bf16x8 bfr = *(const bf16x8*)&BsL[(wv * 32 + j * 16 + l15) * 40 + quad * 8];
            acc[j] = __builtin_amdgcn_mfma_f32_16x16x32_bf16(af, bfr, acc[j], 0, 0, 0);
        }
        __syncthreads();
    }
    #pragma unroll
    for (int j = 0; j < 2; ++j) {
        int o = o0 + wv * 32 + j * 16 + l15;
        #pragma unroll
        for (int r = 0; r < 4; ++r)
            atomicAdd(&out[(size_t)(quad * 4 + r) * 512 + o], acc[j][r]);
    }
}

// ---------------------------------------------------------------------------
extern "C" void kernel_launch(void* const* d_in, const int* in_sizes, int n_in,
                              void* d_out, int out_size, void* d_ws, size_t ws_size,
                              hipStream_t stream) {
    const float* x    = (const float*)d_in[0];
    const float* phi  = (const float*)d_in[1];
    const float* W1   = (const float*)d_in[2];
    const float* b1   = (const float*)d_in[3];
    const float* W2   = (const float*)d_in[4];
    const float* b2   = (const float*)d_in[5];
    const float* Wout = (const float*)d_in[6];
    const float* bout = (const float*)d_in[7];
    float* out = (float*)d_out;

    // Workspace (~35.3 MB)
    char* base = (char*)d_ws;
    float* logits = (float*)(base + 0);           // 11,173,888
    u16*   DwT    = (u16*)(base + 11173888);      //  5,767,168
    u16*   CwB    = (u16*)(base + 16941056);      //  5,767,168
    u16*   T1b    = (u16*)(base + 22708224);      //  5,767,168
    u16*   Gb     = (u16*)(base + 28475392);      //  5,767,168
    u16*   xh     = (u16*)(base + 34242560);      //    262,144
    u16*   xl     = (u16*)(base + 34504704);      //    262,144
    float* Y      = (float*)(base + 34766848);    //    524,288

    k_prep    <<<dim3(128), 256, 0, stream>>>(x, xh, xl);
    k_lt1     <<<dim3(1056), 256, 0, stream>>>(xh, xl, phi, W1, logits, DwT, T1b);
    k_cw      <<<dim3(528), 512, 0, stream>>>(logits, CwB, b2, bout, Y, out);
    k_mid     <<<dim3(1536), 256, 0, stream>>>(T1b, DwT, CwB, b1, Gb);
    k_ygemm   <<<dim3(512), 256, 0, stream>>>(Gb, W2, Y);
    k_outgemm <<<dim3(4, 128), 256, 0, stream>>>(Y, Wout, out);
}